// Round 1
// baseline (85.074 us; speedup 1.0000x reference)
//
#include <hip/hip_runtime.h>
#include <hip/hip_bf16.h>
#include <math.h>

// Problem constants (from reference): B=8, T=128, A=6, F=64, D=64, H=4, hd=16
// N = B*T*F = 65536 sequences of length A=6.
//
// Algebraic collapse:
//   hid_a = x_a * w + b                     (w = embed_w[:,0], b = embed_b)
//   q_a = x_a*wq + cq, etc. (wq = Wq@w, cq = Wq@b + bq)
//   S_ij(head h) = scale*(q_i . k_j)_h = a_h x_i x_j + b_h x_i + c_h x_j + d_h
//   o_i(head h)  = s_ih * wv_h + cv_h,  s_ih = sum_j attn_ij x_j   (sum attn = 1)
//   z_i = Wout@o_i + bout = sum_h s_ih u_h + c0
//   y_i = z_i + hid_i = M @ t_i,  t_i = [s_i0..s_i3, x_i, 1],  M is 64x6
//   LN+final proj: out_i = pc . t_i / sqrt(t_i^T Gc t_i + eps) + C
//   with Mc = column-centered M, Gc = Mc^T Mc / 64 (PSD -> no cancellation),
//   pc = (out_w*ln_g)^T Mc, C = out_w . ln_b + out_b.
//
// d_ws layout (floats):
//   [0..3]=a_h  [4..7]=b_h  [8..11]=c_h  [12..15]=d_h
//   [16..21]=pc[6]   [22..57]=Gc[6][6] row-major   [58]=C

#define DD 64

__global__ void sca_precompute(
    const float* __restrict__ embed_w,   // [64,1]
    const float* __restrict__ embed_b,   // [64]
    const float* __restrict__ in_proj_w, // [192,64]
    const float* __restrict__ in_proj_b, // [192]
    const float* __restrict__ out_proj_w,// [64,64]
    const float* __restrict__ out_proj_b,// [64]
    const float* __restrict__ ln_g,      // [64]
    const float* __restrict__ ln_b,      // [64]
    const float* __restrict__ out_w,     // [1,64]
    const float* __restrict__ out_b,     // [1]
    float* __restrict__ K)
{
    __shared__ float wqkv[192];   // [Wq@w ; Wk@w ; Wv@w]
    __shared__ float cqkv[192];   // [Wq@b+bq ; ...]
    __shared__ float Mc[6][DD];   // M transposed (col j in row j), then centered
    __shared__ float mcol[6];

    const int tid = threadIdx.x;

    // ---- stage 1: project embed through in_proj (192 rows) ----
    if (tid < 192) {
        float sw = 0.f, sc = 0.f;
        #pragma unroll
        for (int e = 0; e < DD; ++e) {
            float wrow = in_proj_w[tid * DD + e];
            sw += wrow * embed_w[e];
            sc += wrow * embed_b[e];
        }
        wqkv[tid] = sw;
        cqkv[tid] = sc + in_proj_b[tid];
    }
    __syncthreads();

    // ---- stage 2: per-head bilinear score coefficients ----
    if (tid < 4) {
        const float scale = 0.25f; // 1/sqrt(16)
        float a = 0.f, bb = 0.f, c = 0.f, d = 0.f;
        #pragma unroll
        for (int k = 0; k < 16; ++k) {
            int qd = tid * 16 + k;
            float wq = wqkv[qd],      cq = cqkv[qd];
            float wk = wqkv[64 + qd], ck = cqkv[64 + qd];
            a  += wq * wk;
            bb += wq * ck;
            c  += cq * wk;
            d  += cq * ck;
        }
        K[0 + tid]  = a  * scale;
        K[4 + tid]  = bb * scale;
        K[8 + tid]  = c  * scale;
        K[12 + tid] = d  * scale;
    }

    // ---- stage 3: build M columns (one thread per output dim d) ----
    if (tid < DD) {
        int d = tid;
        #pragma unroll
        for (int h = 0; h < 4; ++h) {
            float s = 0.f;
            #pragma unroll
            for (int k = 0; k < 16; ++k) {
                int e = h * 16 + k;
                s += out_proj_w[d * DD + e] * wqkv[128 + e];
            }
            Mc[h][d] = s;                        // u_h[d]
        }
        float c0 = out_proj_b[d];
        #pragma unroll
        for (int e = 0; e < DD; ++e)
            c0 += out_proj_w[d * DD + e] * cqkv[128 + e];
        Mc[4][d] = embed_w[d];                   // residual: x_i * w
        Mc[5][d] = c0 + embed_b[d];              // constant column
    }
    __syncthreads();

    // ---- column means ----
    if (tid < 6) {
        float s = 0.f;
        for (int d = 0; d < DD; ++d) s += Mc[tid][d];
        mcol[tid] = s * (1.f / DD);
    }
    __syncthreads();

    // ---- center columns ----
    if (tid < DD) {
        #pragma unroll
        for (int j = 0; j < 6; ++j) Mc[j][tid] -= mcol[j];
    }
    __syncthreads();

    // ---- Gc (36), pc (6), C (1) ----
    if (tid < 36) {
        int j = tid / 6, k2 = tid % 6;
        float s = 0.f;
        for (int d = 0; d < DD; ++d) s += Mc[j][d] * Mc[k2][d];
        K[22 + tid] = s * (1.f / DD);
    } else if (tid < 42) {
        int j = tid - 36;
        float s = 0.f;
        for (int d = 0; d < DD; ++d) s += out_w[d] * ln_g[d] * Mc[j][d];
        K[16 + j] = s;
    } else if (tid == 42) {
        float s = out_b[0];
        for (int d = 0; d < DD; ++d) s += out_w[d] * ln_b[d];
        K[58] = s;
    }
}

__global__ __launch_bounds__(256) void sca_main(
    const float* __restrict__ x,   // [B,T,A,F] flat
    const float* __restrict__ K,   // derived constants (59 floats)
    float* __restrict__ out,       // [B,T,A,F] flat
    int N)                         // B*T*F sequences
{
    int n = blockIdx.x * blockDim.x + threadIdx.x;
    if (n >= N) return;

    // token a of sequence n lives at bt*384 + a*64 + f  (bt = n>>6, f = n&63)
    const int base = (n >> 6) * 384 + (n & 63);

    float xv[6];
    #pragma unroll
    for (int a = 0; a < 6; ++a) xv[a] = x[base + (a << 6)];

    // ---- attention: per head, per query row ----
    float s[6][4]; // s[i][h] = sum_j attn_ij * x_j
    #pragma unroll
    for (int h = 0; h < 4; ++h) {
        const float ah = K[h], bh = K[4 + h], ch = K[8 + h], dh = K[12 + h];
        float fj[6], gj[6]; // S_ij = x_i * fj[j] + gj[j]
        #pragma unroll
        for (int j = 0; j < 6; ++j) {
            fj[j] = ah * xv[j] + bh;
            gj[j] = ch * xv[j] + dh;
        }
        #pragma unroll
        for (int i = 0; i < 6; ++i) {
            float sc[6];
            float mx = -1e30f;
            #pragma unroll
            for (int j = 0; j < 6; ++j) {
                if (j == i) continue;              // diagonal masked to -inf
                sc[j] = xv[i] * fj[j] + gj[j];
                mx = fmaxf(mx, sc[j]);
            }
            float Z = 0.f, sv = 0.f;
            #pragma unroll
            for (int j = 0; j < 6; ++j) {
                if (j == i) continue;
                float e = __expf(sc[j] - mx);
                Z += e;
                sv += e * xv[j];
            }
            s[i][h] = sv / Z;
        }
    }

    // ---- LN + output projection via 6-dim quadratic form ----
    float pc[6];
    #pragma unroll
    for (int j = 0; j < 6; ++j) pc[j] = K[16 + j];
    float Gc[6][6];
    #pragma unroll
    for (int j = 0; j < 36; ++j) Gc[j / 6][j % 6] = K[22 + j];
    const float C = K[58];

    #pragma unroll
    for (int i = 0; i < 6; ++i) {
        float t[6] = { s[i][0], s[i][1], s[i][2], s[i][3], xv[i], 1.f };
        float num = 0.f, var = 0.f;
        #pragma unroll
        for (int j = 0; j < 6; ++j) {
            num += pc[j] * t[j];
            float rv = 0.f;
            #pragma unroll
            for (int k = 0; k < 6; ++k) rv += Gc[j][k] * t[k];
            var += rv * t[j];
        }
        out[base + (i << 6)] = num * rsqrtf(var + 1e-5f) + C;
    }
}

extern "C" void kernel_launch(void* const* d_in, const int* in_sizes, int n_in,
                              void* d_out, int out_size, void* d_ws, size_t ws_size,
                              hipStream_t stream) {
    const float* x          = (const float*)d_in[0];
    const float* embed_w    = (const float*)d_in[1];
    const float* embed_b    = (const float*)d_in[2];
    const float* in_proj_w  = (const float*)d_in[3];
    const float* in_proj_b  = (const float*)d_in[4];
    const float* out_proj_w = (const float*)d_in[5];
    const float* out_proj_b = (const float*)d_in[6];
    const float* ln_g       = (const float*)d_in[7];
    const float* ln_b       = (const float*)d_in[8];
    const float* out_w      = (const float*)d_in[9];
    const float* out_b      = (const float*)d_in[10];

    float* K = (float*)d_ws;            // 59 floats of derived constants
    float* out = (float*)d_out;

    const int N = in_sizes[0] / 6;      // B*T*F = 65536

    sca_precompute<<<1, 192, 0, stream>>>(embed_w, embed_b, in_proj_w, in_proj_b,
                                          out_proj_w, out_proj_b, ln_g, ln_b,
                                          out_w, out_b, K);

    const int block = 256;
    const int grid = (N + block - 1) / block;
    sca_main<<<grid, block, 0, stream>>>(x, K, out, N);
}

// Round 2
// 84.113 us; speedup vs baseline: 1.0114x; 1.0114x over previous
//
#include <hip/hip_runtime.h>
#include <hip/hip_bf16.h>
#include <math.h>

// Problem: B=8, T=128, A=6, F=64, D=64, H=4, hd=16.  N = B*T*F = 65536
// sequences of A=6 tokens, each token a single scalar x_a.
//
// Full algebraic collapse (see round-1 derivation):
//   S_ij(h) = a_h x_i x_j + b_h x_i + c_h x_j + d_h   (4 scalars/head)
//   o_i collapses to s_ih = sum_j attn_ij x_j (sum attn = 1), and
//   y_i = M @ t_i with t_i = [s_i0..s_i3, x_i, 1], M = 64x6 precomputable.
//   LN + final proj:  out_i = pc . t_i / sqrt(t_i^T Gc t_i + eps) + C,
//   Gc = Mc^T Mc / 64 (Mc column-centered M, PSD -> stable), symmetric ->
//   only 21 unique coefficients (off-diagonals pre-doubled).
//
// Round-2 change: SINGLE kernel. Every block redundantly recomputes the
// ~60 derived constants into LDS (~25K FLOPs; weights are L2/L3-resident),
// eliminating the second launch, the precompute->main serialization, and
// all d_ws usage.
//
// sK layout: [0..3]=a_h [4..7]=b_h [8..11]=c_h [12..15]=d_h
//            [16..21]=pc [22..42]=G2 (upper-tri, off-diag x2) [43]=C

#define DD 64

__global__ __launch_bounds__(256) void sca_fused(
    const float* __restrict__ x,         // [B,T,A,F] flat
    const float* __restrict__ embed_w,   // [64,1]
    const float* __restrict__ embed_b,   // [64]
    const float* __restrict__ in_proj_w, // [192,64]
    const float* __restrict__ in_proj_b, // [192]
    const float* __restrict__ out_proj_w,// [64,64]
    const float* __restrict__ out_proj_b,// [64]
    const float* __restrict__ ln_g,      // [64]
    const float* __restrict__ ln_b,      // [64]
    const float* __restrict__ out_w,     // [1,64]
    const float* __restrict__ out_b,     // [1]
    float* __restrict__ out,             // [B,T,A,F] flat
    int N)
{
    __shared__ float wqkv[192];   // [Wq@w ; Wk@w ; Wv@w]
    __shared__ float cqkv[192];   // [Wq@b+bq ; ...]
    __shared__ float Mc[6][DD];   // columns of M, then centered
    __shared__ float mcol[6];
    __shared__ float sK[44];

    const int tid = threadIdx.x;

    // ---- stage 1: embed through in_proj (192 rows) ----
    if (tid < 192) {
        float sw = 0.f, sc = 0.f;
        #pragma unroll
        for (int e = 0; e < DD; ++e) {
            float wr = in_proj_w[tid * DD + e];
            sw += wr * embed_w[e];
            sc += wr * embed_b[e];
        }
        wqkv[tid] = sw;
        cqkv[tid] = sc + in_proj_b[tid];
    }
    __syncthreads();

    // ---- stage 2: per-head bilinear score coefficients ----
    if (tid < 4) {
        const float scale = 0.25f; // 1/sqrt(16)
        float a = 0.f, bb = 0.f, c = 0.f, d = 0.f;
        #pragma unroll
        for (int k = 0; k < 16; ++k) {
            int qd = tid * 16 + k;
            float wq = wqkv[qd],      cq = cqkv[qd];
            float wk = wqkv[64 + qd], ck = cqkv[64 + qd];
            a  += wq * wk;
            bb += wq * ck;
            c  += cq * wk;
            d  += cq * ck;
        }
        sK[0 + tid]  = a  * scale;
        sK[4 + tid]  = bb * scale;
        sK[8 + tid]  = c  * scale;
        sK[12 + tid] = d  * scale;
    }

    // ---- stage 3: columns of M (one thread per output dim d) ----
    if (tid < DD) {
        int d = tid;
        #pragma unroll
        for (int h = 0; h < 4; ++h) {
            float s = 0.f;
            #pragma unroll
            for (int k = 0; k < 16; ++k) {
                int e = h * 16 + k;
                s += out_proj_w[d * DD + e] * wqkv[128 + e];
            }
            Mc[h][d] = s;                       // u_h[d]
        }
        float c0 = out_proj_b[d];
        #pragma unroll
        for (int e = 0; e < DD; ++e)
            c0 += out_proj_w[d * DD + e] * cqkv[128 + e];
        Mc[4][d] = embed_w[d];                  // residual x_i * w
        Mc[5][d] = c0 + embed_b[d];             // constant column
    }
    __syncthreads();

    if (tid < 6) {
        float s = 0.f;
        for (int d = 0; d < DD; ++d) s += Mc[tid][d];
        mcol[tid] = s * (1.f / DD);
    }
    __syncthreads();

    if (tid < DD) {
        #pragma unroll
        for (int j = 0; j < 6; ++j) Mc[j][tid] -= mcol[j];
    }
    __syncthreads();

    // ---- G2 (21 upper-tri, off-diag doubled), pc (6), C (1) ----
    if (tid < 21) {
        int j = 0, rr = tid;
        while (rr > 5 - j) { rr -= (6 - j); ++j; }
        int k = j + rr;
        float s = 0.f;
        for (int d = 0; d < DD; ++d) s += Mc[j][d] * Mc[k][d];
        sK[22 + tid] = s * (1.f / DD) * (j == k ? 1.f : 2.f);
    } else if (tid < 27) {
        int j = tid - 21;
        float s = 0.f;
        for (int d = 0; d < DD; ++d) s += out_w[d] * ln_g[d] * Mc[j][d];
        sK[16 + j] = s;
    } else if (tid == 27) {
        float s = out_b[0];
        for (int d = 0; d < DD; ++d) s += out_w[d] * ln_b[d];
        sK[43] = s;
    }
    __syncthreads();

    // =========================== main ===========================
    const int n = blockIdx.x * 256 + tid;
    if (n >= N) return;

    // token a of sequence n: bt*384 + a*64 + f  (bt = n>>6, f = n&63)
    const int base = (n >> 6) * 384 + (n & 63);

    float xv[6];
    #pragma unroll
    for (int a = 0; a < 6; ++a) xv[a] = x[base + (a << 6)];

    float ka[4], kb[4], kc[4], kd[4];
    #pragma unroll
    for (int h = 0; h < 4; ++h) {
        ka[h] = sK[h];      kb[h] = sK[4 + h];
        kc[h] = sK[8 + h];  kd[h] = sK[12 + h];
    }
    float pcv[6];
    #pragma unroll
    for (int j = 0; j < 6; ++j) pcv[j] = sK[16 + j];
    float G2[21];
    #pragma unroll
    for (int r = 0; r < 21; ++r) G2[r] = sK[22 + r];
    const float C = sK[43];

    // ---- attention ----
    float s[6][4];
    #pragma unroll
    for (int h = 0; h < 4; ++h) {
        float fj[6], gj[6];
        #pragma unroll
        for (int j = 0; j < 6; ++j) {
            fj[j] = ka[h] * xv[j] + kb[h];
            gj[j] = kc[h] * xv[j] + kd[h];
        }
        #pragma unroll
        for (int i = 0; i < 6; ++i) {
            float sc[6];
            float mx = -1e30f;
            #pragma unroll
            for (int j = 0; j < 6; ++j) {
                if (j == i) continue;            // diagonal masked
                sc[j] = xv[i] * fj[j] + gj[j];
                mx = fmaxf(mx, sc[j]);
            }
            float Z = 0.f, sv = 0.f;
            #pragma unroll
            for (int j = 0; j < 6; ++j) {
                if (j == i) continue;
                float e = __expf(sc[j] - mx);
                Z += e;
                sv += e * xv[j];
            }
            s[i][h] = sv / Z;
        }
    }

    // ---- LN + output projection: 6-dim quadratic form ----
    #pragma unroll
    for (int i = 0; i < 6; ++i) {
        float t[6] = { s[i][0], s[i][1], s[i][2], s[i][3], xv[i], 1.f };
        float num = 0.f, var = 0.f;
        int idx = 0;
        #pragma unroll
        for (int j = 0; j < 6; ++j) {
            num += pcv[j] * t[j];
            #pragma unroll
            for (int k = j; k < 6; ++k) {
                var += G2[idx++] * t[j] * t[k];
            }
        }
        out[base + (i << 6)] = num * rsqrtf(var + 1e-5f) + C;
    }
}

extern "C" void kernel_launch(void* const* d_in, const int* in_sizes, int n_in,
                              void* d_out, int out_size, void* d_ws, size_t ws_size,
                              hipStream_t stream) {
    const float* x          = (const float*)d_in[0];
    const float* embed_w    = (const float*)d_in[1];
    const float* embed_b    = (const float*)d_in[2];
    const float* in_proj_w  = (const float*)d_in[3];
    const float* in_proj_b  = (const float*)d_in[4];
    const float* out_proj_w = (const float*)d_in[5];
    const float* out_proj_b = (const float*)d_in[6];
    const float* ln_g       = (const float*)d_in[7];
    const float* ln_b       = (const float*)d_in[8];
    const float* out_w      = (const float*)d_in[9];
    const float* out_b      = (const float*)d_in[10];

    float* out = (float*)d_out;
    const int N = in_sizes[0] / 6;      // B*T*F = 65536

    const int block = 256;
    const int grid = (N + block - 1) / block;   // 256 blocks
    sca_fused<<<grid, block, 0, stream>>>(x, embed_w, embed_b, in_proj_w,
                                          in_proj_b, out_proj_w, out_proj_b,
                                          ln_g, ln_b, out_w, out_b, out, N);
}